// Round 15
// baseline (196.941 us; speedup 1.0000x reference)
//
#include <hip/hip_runtime.h>
#include <hip/hip_bf16.h>

// Problem constants
#define T_DIM 1000
#define B_DIM 8
#define E_DIM 1024
#define H_DIM 16
#define HD_DIM 64
#define M_DIM 8000   // T*B rows
#define BH_DIM 128   // B*H heads

typedef float f4 __attribute__((ext_vector_type(4)));
typedef float f16v __attribute__((ext_vector_type(16)));
typedef __bf16 b8 __attribute__((ext_vector_type(8)));
typedef unsigned long long u64;

__device__ __forceinline__ short f2bf(float f) {
  unsigned u = __float_as_uint(f);
  u = u + 0x7fffu + ((u >> 16) & 1u);   // RNE
  return (short)(u >> 16);
}

__device__ __forceinline__ unsigned cvt_pk_bf16(float lo, float hi) {
  unsigned r;
  asm("v_cvt_pk_bf16_f32 %0, %1, %2" : "=v"(r) : "v"(lo), "v"(hi));
  return r;
}

__device__ __forceinline__ void gload_lds16(const void* g, void* l) {
  __builtin_amdgcn_global_load_lds(
      (const __attribute__((address_space(1))) void*)g,
      (__attribute__((address_space(3))) void*)l, 16, 0, 0);
}

__device__ __forceinline__ void cvt_quad(const float* src, short* dst) {
  float4 v = *(const float4*)src;
  short4 o;
  o.x = f2bf(v.x); o.y = f2bf(v.y); o.z = f2bf(v.z); o.w = f2bf(v.w);
  *(short4*)dst = o;
}

// ---------------- weights fp32 -> bf16 (fallback path) ----------------
__global__ void convert_w(const float* __restrict__ a, const float* __restrict__ b,
                          const float* __restrict__ c, const float* __restrict__ d,
                          short* __restrict__ dst) {
  const int nq = (4 * 1048576) / 4;
  for (int i = blockIdx.x * blockDim.x + threadIdx.x; i < nq; i += gridDim.x * blockDim.x) {
    int mat = i >> 18;
    int w = (i & 262143) * 4;
    const float* src = mat == 0 ? a : (mat == 1 ? b : (mat == 2 ? c : d));
    cvt_quad(src + w, dst + i * 4);
  }
}

// ---------------- activation fp32 -> bf16 (fallback path) ----------------
__global__ void convert_x(const float* __restrict__ src, short* __restrict__ dst) {
  const int nq = (M_DIM * E_DIM) / 4;
  for (int i = blockIdx.x * blockDim.x + threadIdx.x; i < nq; i += gridDim.x * blockDim.x) {
    cvt_quad(src + i * 4, dst + i * 4);
  }
}

// ---------------- fused prep: weights + activations + rope table + vtp pad ----------------
__global__ void prep_all(const float* __restrict__ qw, const float* __restrict__ kw,
                         const float* __restrict__ vw, const float* __restrict__ ow,
                         const float* __restrict__ xq, const float* __restrict__ xk,
                         const float* __restrict__ xv,
                         short* __restrict__ wbf, short* __restrict__ xqb,
                         short* __restrict__ xkb, short* __restrict__ xvb,
                         short* __restrict__ vtp_pad,
                         float* __restrict__ ropec, float* __restrict__ ropes) {
  const int WQ = 1048576;              // weight quads (4 matrices x 2^18)
  const int XQ = (M_DIM * E_DIM) / 4;  // 2,048,000 quads per activation
  const int RP = T_DIM * 32;           // 32,000 rope entries
  const int total = WQ + 3 * XQ + RP + 256;
  for (int i = blockIdx.x * blockDim.x + threadIdx.x; i < total; i += gridDim.x * blockDim.x) {
    if (i < WQ) {
      int mat = i >> 18;
      int w = (i & 262143) * 4;
      const float* src = mat == 0 ? qw : (mat == 1 ? kw : (mat == 2 ? vw : ow));
      cvt_quad(src + w, wbf + i * 4);
    } else if (i < WQ + 3 * XQ) {
      int j = i - WQ;
      if (j < XQ) cvt_quad(xq + j * 4, xqb + j * 4);
      else if (j < 2 * XQ) cvt_quad(xk + (j - XQ) * 4, xkb + (j - XQ) * 4);
      else cvt_quad(xv + (j - 2 * XQ) * 4, xvb + (j - 2 * XQ) * 4);
    } else if (i < WQ + 3 * XQ + RP) {
      int j = i - WQ - 3 * XQ;
      int t = j >> 5, f = j & 31;
      double inv = pow(10000.0, -(double)f / 32.0);
      double a = (double)t * inv;
      ropec[j] = (float)cos(a);
      ropes[j] = (float)sin(a);
    } else {
      vtp_pad[i - WQ - 3 * XQ - RP] = 0;   // zero 512B tail pad of vtp
    }
  }
}

// ---------------- RoPE table (fallback path) ----------------
__global__ void rope_tab(float* __restrict__ cosd, float* __restrict__ sind) {
  int i = blockIdx.x * blockDim.x + threadIdx.x;
  if (i >= T_DIM * 32) return;
  int t = i >> 5, f = i & 31;
  double inv = pow(10000.0, -(double)f / 32.0);
  double a = (double)t * inv;
  cosd[i] = (float)cos(a);
  sind[i] = (float)sin(a);
}

// ---------------- fused Q/K/V projection GEMM (bf16, BK=64, persistent 2-tile) ----------------
// R11-proven inner structure. Each block processes TWO consecutive work items
// (same m-panel, adjacent n) -> grid 756 fits in one co-residency round: no
// dispatch tail. Bijective XCD chunk swizzle (works for grid % 8 != 0).
__global__ __launch_bounds__(256, 2) void proj_gemm(
    const short* __restrict__ xqb, const short* __restrict__ xkb,
    const short* __restrict__ xvb, const short* __restrict__ wbf_all,
    const float* __restrict__ qb, const float* __restrict__ kb,
    const float* __restrict__ vb,
    short* __restrict__ qpk, short* __restrict__ kpk, short* __restrict__ vtp,
    const float* __restrict__ ropec, const float* __restrict__ ropes, int mode_base) {
  int nb = gridDim.x;
  int xcd = blockIdx.x & 7, seq = blockIdx.x >> 3;
  int q8 = nb >> 3, r8 = nb & 7;
  int sbid = (xcd < r8 ? xcd * (q8 + 1) : r8 * (q8 + 1) + (xcd - r8) * q8) + seq;

  __shared__ short As[128 * 64];   // 16 KB
  __shared__ short Bs[128 * 64];   // 16 KB
  int tid = threadIdx.x;
  int l = tid & 63, wid = tid >> 6;
  int wr = wid >> 1, wc = wid & 1;
  int lane16 = l & 15, lgrp = l >> 4;
  const float qs = 0.125f * 1.44269504088896f;  // fold 1/ln2 into Q scale

  for (int tt = 0; tt < 2; ++tt) {
    int w = 2 * sbid + tt;               // work id in [0, 2*nb)
    int mode = mode_base + w / 504;
    int wm = w % 504;
    const short* xbf = mode == 0 ? xqb : (mode == 1 ? xkb : xvb);
    const short* W = wbf_all + mode * 1048576;
    const float* bias = mode == 0 ? qb : (mode == 1 ? kb : vb);
    int n0 = (wm & 7) * 128;
    int m0 = (wm >> 3) * 128;

    f4 acc[4][4];
#pragma unroll
    for (int i = 0; i < 4; ++i)
#pragma unroll
      for (int j = 0; j < 4; ++j)
#pragma unroll
        for (int r = 0; r < 4; ++r) acc[i][j][r] = 0.f;

    for (int kt = 0; kt < 16; ++kt) {
      int k0 = kt * 64;
#pragma unroll
      for (int j = 0; j < 4; ++j) {
        int idx = tid + j * 256;       // 0..1023
        int r = idx >> 3, s = idx & 7;
        int c = s ^ (r & 7);           // global chunk held in slot s
        int gm = m0 + r; gm = gm < M_DIM ? gm : (M_DIM - 1);
        gload_lds16(xbf + gm * 1024 + k0 + c * 8, As + idx * 8);
        gload_lds16(W + (n0 + r) * 1024 + k0 + c * 8, Bs + idx * 8);
      }
      __syncthreads();
      b8 af[2][4], bf[2][4];
#pragma unroll
      for (int kk = 0; kk < 2; ++kk) {
#pragma unroll
        for (int mf = 0; mf < 4; ++mf) {
          int row = wr * 64 + mf * 16 + lane16;
          af[kk][mf] = *(const b8*)(As + row * 64 + ((((kk << 2) + lgrp) ^ (row & 7)) << 3));
        }
#pragma unroll
        for (int nf = 0; nf < 4; ++nf) {
          int row = wc * 64 + nf * 16 + lane16;
          bf[kk][nf] = *(const b8*)(Bs + row * 64 + ((((kk << 2) + lgrp) ^ (row & 7)) << 3));
        }
      }
#pragma unroll
      for (int kk = 0; kk < 2; ++kk)
#pragma unroll
        for (int mf = 0; mf < 4; ++mf)
#pragma unroll
          for (int nf = 0; nf < 4; ++nf)
            acc[mf][nf] = __builtin_amdgcn_mfma_f32_16x16x32_bf16(af[kk][mf], bf[kk][nf], acc[mf][nf], 0, 0, 0);
      __syncthreads();
    }

    // epilogue (no LDS access -> next tile's staging is barrier-safe)
    int h = (n0 + wc * 64) >> 6;
    float bv[4];
#pragma unroll
    for (int nf = 0; nf < 4; ++nf) bv[nf] = bias[n0 + wc * 64 + nf * 16 + lane16];

#pragma unroll
    for (int mf = 0; mf < 4; ++mf) {
#pragma unroll
      for (int r = 0; r < 4; ++r) {
        int gm = m0 + wr * 64 + mf * 16 + lgrp * 4 + r;
        bool valid = gm < M_DIM;
        int t = gm >> 3, bb = gm & 7;
        int tc = t < T_DIM ? t : (T_DIM - 1);
        float x0 = acc[mf][0][r] + bv[0];
        float x1 = acc[mf][1][r] + bv[1];
        float x2 = acc[mf][2][r] + bv[2];
        float x3 = acc[mf][3][r] + bv[3];
        if (mode == 0) { x0 *= qs; x1 *= qs; x2 *= qs; x3 *= qs; }
        if (mode < 2) {
          float c0 = ropec[tc * 32 + lane16],      s0 = ropes[tc * 32 + lane16];
          float c1 = ropec[tc * 32 + 16 + lane16], s1 = ropes[tc * 32 + 16 + lane16];
          float y0 = c0 * x0 - s0 * x2;
          float y2 = c0 * x2 + s0 * x0;
          float y1 = c1 * x1 - s1 * x3;
          float y3 = c1 * x3 + s1 * x1;
          if (valid) {
            short* dst = (mode == 0 ? qpk : kpk) + (bb * 16 + h) * 64000 + t * 64;
            dst[lane16]      = f2bf(y0);
            dst[16 + lane16] = f2bf(y1);
            dst[32 + lane16] = f2bf(y2);
            dst[48 + lane16] = f2bf(y3);
          }
        } else if (valid) {
          short* dst = vtp + (bb * 16 + h) * 64000 + t;
          dst[(lane16) * 1000]      = f2bf(x0);
          dst[(16 + lane16) * 1000] = f2bf(x1);
          dst[(32 + lane16) * 1000] = f2bf(x2);
          dst[(48 + lane16) * 1000] = f2bf(x3);
        }
      }
    }
  }
}

// ---------------- fused flash attention (32x32 MFMA, pipelined, max-free) ----------------
__global__ __launch_bounds__(256, 4) void attn_fused(
    const short* __restrict__ qpk, const short* __restrict__ kpk,
    const short* __restrict__ vtp, short* __restrict__ apk) {
  int id = blockIdx.x;
  int xcd = id & 7, seq = id >> 3;
  int bh = xcd * 16 + (seq >> 3);   // 16 heads per XCD, 8 q-tiles each
  int q0 = (seq & 7) * 128;
  int tid = threadIdx.x;
  int l = tid & 63, wid = tid >> 6;
  int l31 = l & 31, hi = l >> 5, l7 = l & 7;
  int qg = q0 + wid * 32 + l31;     // this lane's q (output column)

  __shared__ short Ks[2][64 * 64];  // [k-local][hd], 16B-chunk XOR-swizzled
  __shared__ short Vs[2][64 * 64];  // [d][k-local], 16B-chunk XOR-swizzled

  const short* qh = qpk + bh * 64000;
  const short* kh = kpk + bh * 64000;
  const short* vh = vtp + bh * 64000;

  int srow = tid >> 3;   // staging row (0..31; +32 on second pass)
  int sslot = tid & 7;   // 16B slot within 128B row

  // Q B-frags (hoisted): bq[hc] = Q[q=qg][hd = hc*16 + hi*8 .. +8]
  b8 bq[4];
  {
    int t = qg < T_DIM ? qg : (T_DIM - 1);
#pragma unroll
    for (int hc = 0; hc < 4; ++hc)
      bq[hc] = *(const b8*)(qh + t * 64 + hc * 16 + hi * 8);
  }

  float lrun = 0.f;
  f16v o0, o1;   // O^T[d][q=l31]
#pragma unroll
  for (int i = 0; i < 16; ++i) { o0[i] = 0.f; o1[i] = 0.f; }

  auto stageK = [&](int st, int buf) {
    int s0 = st * 64;
#pragma unroll
    for (int j = 0; j < 2; ++j) {
      int r = srow + j * 32;
      int c = sslot ^ (r & 7);
      gload_lds16(kh + (s0 + r) * 64 + c * 8, &Ks[buf][(j * 256 + tid) * 8]);
    }
  };
  auto stageV = [&](int st, int buf) {
    int s0 = st * 64;
#pragma unroll
    for (int j = 0; j < 2; ++j) {
      int r = srow + j * 32;
      int c = sslot ^ (r & 7);
      gload_lds16(vh + r * 1000 + s0 + c * 8, &Vs[buf][(j * 256 + tid) * 8]);
    }
  };

  // prologue: K(0), V(0), K(1) staged; QK(0) computed into regs
  stageK(0, 0);
  stageV(0, 0);
  stageK(1, 1);
  __syncthreads();

  f16v c0v, c1v;   // S^T for current tile: k 0..31 / 32..63, col q=l31
#pragma unroll
  for (int i = 0; i < 16; ++i) { c0v[i] = 0.f; c1v[i] = 0.f; }
#pragma unroll
  for (int hc = 0; hc < 4; ++hc) {
    int slot = ((2 * hc + hi) ^ l7) << 3;
    b8 a0 = *(const b8*)(Ks[0] + l31 * 64 + slot);
    b8 a1 = *(const b8*)(Ks[0] + (32 + l31) * 64 + slot);
    c0v = __builtin_amdgcn_mfma_f32_32x32x16_bf16(a0, bq[hc], c0v, 0, 0, 0);
    c1v = __builtin_amdgcn_mfma_f32_32x32x16_bf16(a1, bq[hc], c1v, 0, 0, 0);
  }
  // RACE FIX: all waves must finish reading Ks[0] (prologue QK) before any
  // wave's iter-0 stageK(2,0) write can land in Ks[0].
  __syncthreads();

  for (int i = 0; i < 16; ++i) {
    int b = i & 1;
    // stage next tiles early (free buffers this iter: Ks[b], Vs[b^1])
    if (i < 14) stageK(i + 2, b);
    if (i < 15) stageV(i + 1, b ^ 1);

    if (i == 15) {   // mask global k >= 1000 (k-local >= 40): c1v regs 4..15
#pragma unroll
      for (int r = 4; r < 16; ++r) c1v[r] = -1e30f;
    }

    // max-free softmax: P = exp2(S) in place
#pragma unroll
    for (int j = 0; j < 16; ++j) {
      c0v[j] = __builtin_amdgcn_exp2f(c0v[j]);
      c1v[j] = __builtin_amdgcn_exp2f(c1v[j]);
    }
    // partial row-sum (this lane's 32 k's); cross-hi combine deferred
    float ts[8];
#pragma unroll
    for (int j = 0; j < 8; ++j) ts[j] = (c0v[j] + c0v[j + 8]) + (c1v[j] + c1v[j + 8]);
#pragma unroll
    for (int d = 4; d > 0; d >>= 1)
#pragma unroll
      for (int j = 0; j < d; ++j) ts[j] += ts[j + d];
    lrun += ts[0];

    // pack P -> bf16 B-frags via cvt_pk + permlane32_swap
    unsigned u0[8], u1[8];
#pragma unroll
    for (int j = 0; j < 8; ++j) {
      u0[j] = cvt_pk_bf16(c0v[2 * j], c0v[2 * j + 1]);
      u1[j] = cvt_pk_bf16(c1v[2 * j], c1v[2 * j + 1]);
    }
    union { unsigned u[4]; b8 v; } pf[4];
    {
      auto w0 = __builtin_amdgcn_permlane32_swap(u0[0], u0[2], false, false);
      auto w1 = __builtin_amdgcn_permlane32_swap(u0[1], u0[3], false, false);
      pf[0].u[0] = w0[0]; pf[0].u[1] = w1[0]; pf[0].u[2] = w0[1]; pf[0].u[3] = w1[1];
      auto w2 = __builtin_amdgcn_permlane32_swap(u0[4], u0[6], false, false);
      auto w3 = __builtin_amdgcn_permlane32_swap(u0[5], u0[7], false, false);
      pf[1].u[0] = w2[0]; pf[1].u[1] = w3[0]; pf[1].u[2] = w2[1]; pf[1].u[3] = w3[1];
      auto w4 = __builtin_amdgcn_permlane32_swap(u1[0], u1[2], false, false);
      auto w5 = __builtin_amdgcn_permlane32_swap(u1[1], u1[3], false, false);
      pf[2].u[0] = w4[0]; pf[2].u[1] = w5[0]; pf[2].u[2] = w4[1]; pf[2].u[3] = w5[1];
      auto w6 = __builtin_amdgcn_permlane32_swap(u1[4], u1[6], false, false);
      auto w7 = __builtin_amdgcn_permlane32_swap(u1[5], u1[7], false, false);
      pf[3].u[0] = w6[0]; pf[3].u[1] = w7[0]; pf[3].u[2] = w6[1]; pf[3].u[3] = w7[1];
    }

    // QK(i+1) into freed c regs (consumed next iter -> full pipeline distance)
    if (i < 15) {
      const short* Kb = Ks[b ^ 1];
#pragma unroll
      for (int j = 0; j < 16; ++j) { c0v[j] = 0.f; c1v[j] = 0.f; }
      __builtin_amdgcn_s_setprio(1);
#pragma unroll
      for (int hc = 0; hc < 4; ++hc) {
        int slot = ((2 * hc + hi) ^ l7) << 3;
        b8 a0 = *(const b8*)(Kb + l31 * 64 + slot);
        b8 a1 = *(const b8*)(Kb + (32 + l31) * 64 + slot);
        c0v = __builtin_amdgcn_mfma_f32_32x32x16_bf16(a0, bq[hc], c0v, 0, 0, 0);
        c1v = __builtin_amdgcn_mfma_f32_32x32x16_bf16(a1, bq[hc], c1v, 0, 0, 0);
      }
      __builtin_amdgcn_s_setprio(0);
    }

    // PV(i): O^T += V^T P^T
    {
      const short* Vb = Vs[b];
      __builtin_amdgcn_s_setprio(1);
#pragma unroll
      for (int ck = 0; ck < 4; ++ck) {
        int slot = ((2 * ck + hi) ^ l7) << 3;
        b8 av0 = *(const b8*)(Vb + l31 * 64 + slot);
        b8 av1 = *(const b8*)(Vb + (32 + l31) * 64 + slot);
        o0 = __builtin_amdgcn_mfma_f32_32x32x16_bf16(av0, pf[ck].v, o0, 0, 0, 0);
        o1 = __builtin_amdgcn_mfma_f32_32x32x16_bf16(av1, pf[ck].v, o1, 0, 0, 0);
      }
      __builtin_amdgcn_s_setprio(0);
    }
    __syncthreads();
  }

  // epilogue: combine lrun across hi halves; lane owns q = qg
  lrun += __shfl_xor(lrun, 32, 64);
  if (qg < T_DIM) {
    float linv = 1.f / lrun;
    int bb = bh >> 4, hh = bh & 15;
    short* dst = apk + (qg * 8 + bb) * 1024 + hh * 64;
#pragma unroll
    for (int rq = 0; rq < 4; ++rq) {
      int d0 = 8 * rq + 4 * hi;
      short4 w0, w1;
      w0.x = f2bf(o0[rq * 4 + 0] * linv);
      w0.y = f2bf(o0[rq * 4 + 1] * linv);
      w0.z = f2bf(o0[rq * 4 + 2] * linv);
      w0.w = f2bf(o0[rq * 4 + 3] * linv);
      w1.x = f2bf(o1[rq * 4 + 0] * linv);
      w1.y = f2bf(o1[rq * 4 + 1] * linv);
      w1.z = f2bf(o1[rq * 4 + 2] * linv);
      w1.w = f2bf(o1[rq * 4 + 3] * linv);
      *(short4*)(dst + d0) = w0;
      *(short4*)(dst + 32 + d0) = w1;
    }
  }
}

// ---------------- output projection GEMM (BK=64, 2-barrier, swizzled) ----------------
__global__ __launch_bounds__(256, 2) void out_gemm(
    const short* __restrict__ apk, const short* __restrict__ wo,
    const float* __restrict__ ob, float* __restrict__ out) {
  int id = blockIdx.x;
  int w = (id & 7) * 63 + (id >> 3);   // XCD-contiguous work index
  int n0 = (w & 7) * 128;
  int m0 = (w >> 3) * 128;
  __shared__ short As[128 * 64];
  __shared__ short Bs[128 * 64];
  int tid = threadIdx.x;
  int l = tid & 63, wid = tid >> 6;
  int wr = wid >> 1, wc = wid & 1;
  int lane16 = l & 15, lgrp = l >> 4;

  f4 acc[4][4];
#pragma unroll
  for (int i = 0; i < 4; ++i)
#pragma unroll
    for (int j = 0; j < 4; ++j)
#pragma unroll
      for (int r = 0; r < 4; ++r) acc[i][j][r] = 0.f;

  for (int kt = 0; kt < 16; ++kt) {
    int k0 = kt * 64;
#pragma unroll
    for (int j = 0; j < 4; ++j) {
      int idx = tid + j * 256;
      int r = idx >> 3, s = idx & 7;
      int c = s ^ (r & 7);
      int gm = m0 + r; gm = gm < M_DIM ? gm : (M_DIM - 1);
      gload_lds16(apk + gm * 1024 + k0 + c * 8, As + idx * 8);
      gload_lds16(wo + (n0 + r) * 1024 + k0 + c * 8, Bs + idx * 8);
    }
    __syncthreads();
    b8 af[2][4], bf[2][4];
#pragma unroll
    for (int kk = 0; kk < 2; ++kk) {
#pragma unroll
      for (int mf = 0; mf < 4; ++mf) {
        int row = wr * 64 + mf * 16 + lane16;
        af[kk][mf] = *(const b8*)(As + row * 64 + ((((kk << 2) + lgrp) ^ (row & 7)) << 3));
      }
#pragma unroll
      for (int nf = 0; nf < 4; ++nf) {
        int row = wc * 64 + nf * 16 + lane16;
        bf[kk][nf] = *(const b8*)(Bs + row * 64 + ((((kk << 2) + lgrp) ^ (row & 7)) << 3));
      }
    }
#pragma unroll
    for (int kk = 0; kk < 2; ++kk)
#pragma unroll
      for (int mf = 0; mf < 4; ++mf)
#pragma unroll
        for (int nf = 0; nf < 4; ++nf)
          acc[mf][nf] = __builtin_amdgcn_mfma_f32_16x16x32_bf16(af[kk][mf], bf[kk][nf], acc[mf][nf], 0, 0, 0);
    __syncthreads();
  }

  float bv[4];
#pragma unroll
  for (int nf = 0; nf < 4; ++nf) bv[nf] = ob[n0 + wc * 64 + nf * 16 + lane16];
#pragma unroll
  for (int mf = 0; mf < 4; ++mf) {
#pragma unroll
    for (int r = 0; r < 4; ++r) {
      int gm = m0 + wr * 64 + mf * 16 + lgrp * 4 + r;
      if (gm < M_DIM) {
#pragma unroll
        for (int nf = 0; nf < 4; ++nf)
          out[gm * 1024 + n0 + wc * 64 + nf * 16 + lane16] = acc[mf][nf][r] + bv[nf];
      }
    }
  }
}

// ---------------- launch ----------------
extern "C" void kernel_launch(void* const* d_in, const int* in_sizes, int n_in,
                              void* d_out, int out_size, void* d_ws, size_t ws_size,
                              hipStream_t stream) {
  const float* xq = (const float*)d_in[0];
  const float* xk = (const float*)d_in[1];
  const float* xv = (const float*)d_in[2];
  const float* qw = (const float*)d_in[3];
  const float* kw = (const float*)d_in[4];
  const float* vw = (const float*)d_in[5];
  const float* ow = (const float*)d_in[6];
  const float* qb = (const float*)d_in[7];
  const float* kb = (const float*)d_in[8];
  const float* vb = (const float*)d_in[9];
  const float* ob = (const float*)d_in[10];
  float* out = (float*)d_out;
  char* ws = (char*)d_ws;

  // base workspace layout (~74.2 MB)
  short* wbf   = (short*)(ws);                         // 4 * 1Mi bf16 = 8 MB
  float* ropec = (float*)(ws + 8388608);               // 32000 f32
  float* ropes = (float*)(ws + 8516608);               // 32000 f32
  short* qpk   = (short*)(ws + 8644608);               // (BH,T,HD) bf16
  short* kpk   = (short*)(ws + 8644608 + 16384512);
  short* vtp   = (short*)(ws + 8644608 + 2 * 16384512);// (BH,HD,T) bf16 (+512B pad)
  short* apk   = (short*)(ws + 8644608 + 3 * 16384512);// (T*B,E) bf16
  const size_t BASE = 8644608 + (size_t)4 * 16384512;  // 74,182,656

  const size_t XB = (size_t)M_DIM * E_DIM * 2;         // 16,384,000 B per bf16 X
  if (ws_size >= BASE + 3 * XB) {
    // fused path: prep (converts + rope + pad) -> 3-mode persistent proj -> attn -> out
    short* xqb = (short*)(ws + BASE);
    short* xkb = (short*)(ws + BASE + XB);
    short* xvb = (short*)(ws + BASE + 2 * XB);
    prep_all<<<2048, 256, 0, stream>>>(qw, kw, vw, ow, xq, xk, xv, wbf, xqb, xkb, xvb,
                                       vtp + 8192000, ropec, ropes);
    proj_gemm<<<dim3(756), dim3(256), 0, stream>>>(xqb, xkb, xvb, wbf, qb, kb, vb,
                                                   qpk, kpk, vtp, ropec, ropes, 0);
  } else {
    // fallback: proven alternating sequence, xbf shares the apk slot
    hipMemsetAsync((char*)vtp + 2 * 8192000, 0, 512, stream);
    rope_tab<<<125, 256, 0, stream>>>(ropec, ropes);
    short* xbf = apk;
    convert_w<<<2048, 256, 0, stream>>>(qw, kw, vw, ow, wbf);
    const float* xs[3] = {xq, xk, xv};
    for (int mode = 0; mode < 3; ++mode) {
      convert_x<<<2048, 256, 0, stream>>>(xs[mode], xbf);
      proj_gemm<<<dim3(252), dim3(256), 0, stream>>>(xbf, xbf, xbf, wbf, qb, kb, vb,
                                                     qpk, kpk, vtp, ropec, ropes, mode);
    }
  }
  attn_fused<<<dim3(1024), dim3(256), 0, stream>>>(qpk, kpk, vtp, apk);
  out_gemm<<<dim3(504), dim3(256), 0, stream>>>(apk, wbf + 3 * 1048576, ob, out);
}

// Round 16
// 172.616 us; speedup vs baseline: 1.1409x; 1.1409x over previous
//
#include <hip/hip_runtime.h>
#include <hip/hip_bf16.h>

// Problem constants
#define T_DIM 1000
#define B_DIM 8
#define E_DIM 1024
#define H_DIM 16
#define HD_DIM 64
#define M_DIM 8000   // T*B rows
#define BH_DIM 128   // B*H heads

typedef float f4 __attribute__((ext_vector_type(4)));
typedef float f16v __attribute__((ext_vector_type(16)));
typedef __bf16 b8 __attribute__((ext_vector_type(8)));
typedef unsigned long long u64;

__device__ __forceinline__ short f2bf(float f) {
  unsigned u = __float_as_uint(f);
  u = u + 0x7fffu + ((u >> 16) & 1u);   // RNE
  return (short)(u >> 16);
}

__device__ __forceinline__ unsigned cvt_pk_bf16(float lo, float hi) {
  unsigned r;
  asm("v_cvt_pk_bf16_f32 %0, %1, %2" : "=v"(r) : "v"(lo), "v"(hi));
  return r;
}

__device__ __forceinline__ void gload_lds16(const void* g, void* l) {
  __builtin_amdgcn_global_load_lds(
      (const __attribute__((address_space(1))) void*)g,
      (__attribute__((address_space(3))) void*)l, 16, 0, 0);
}

__device__ __forceinline__ void cvt_quad(const float* src, short* dst) {
  float4 v = *(const float4*)src;
  short4 o;
  o.x = f2bf(v.x); o.y = f2bf(v.y); o.z = f2bf(v.z); o.w = f2bf(v.w);
  *(short4*)dst = o;
}

// ---------------- weights fp32 -> bf16 (fallback path) ----------------
__global__ void convert_w(const float* __restrict__ a, const float* __restrict__ b,
                          const float* __restrict__ c, const float* __restrict__ d,
                          short* __restrict__ dst) {
  const int nq = (4 * 1048576) / 4;
  for (int i = blockIdx.x * blockDim.x + threadIdx.x; i < nq; i += gridDim.x * blockDim.x) {
    int mat = i >> 18;
    int w = (i & 262143) * 4;
    const float* src = mat == 0 ? a : (mat == 1 ? b : (mat == 2 ? c : d));
    cvt_quad(src + w, dst + i * 4);
  }
}

// ---------------- activation fp32 -> bf16 (fallback path) ----------------
__global__ void convert_x(const float* __restrict__ src, short* __restrict__ dst) {
  const int nq = (M_DIM * E_DIM) / 4;
  for (int i = blockIdx.x * blockDim.x + threadIdx.x; i < nq; i += gridDim.x * blockDim.x) {
    cvt_quad(src + i * 4, dst + i * 4);
  }
}

// ---------------- fused prep: weights + activations + rope table + vtp pad ----------------
__global__ void prep_all(const float* __restrict__ qw, const float* __restrict__ kw,
                         const float* __restrict__ vw, const float* __restrict__ ow,
                         const float* __restrict__ xq, const float* __restrict__ xk,
                         const float* __restrict__ xv,
                         short* __restrict__ wbf, short* __restrict__ xqb,
                         short* __restrict__ xkb, short* __restrict__ xvb,
                         short* __restrict__ vtp_pad,
                         float* __restrict__ ropec, float* __restrict__ ropes) {
  const int WQ = 1048576;              // weight quads (4 matrices x 2^18)
  const int XQ = (M_DIM * E_DIM) / 4;  // 2,048,000 quads per activation
  const int RP = T_DIM * 32;           // 32,000 rope entries
  const int total = WQ + 3 * XQ + RP + 256;
  for (int i = blockIdx.x * blockDim.x + threadIdx.x; i < total; i += gridDim.x * blockDim.x) {
    if (i < WQ) {
      int mat = i >> 18;
      int w = (i & 262143) * 4;
      const float* src = mat == 0 ? qw : (mat == 1 ? kw : (mat == 2 ? vw : ow));
      cvt_quad(src + w, wbf + i * 4);
    } else if (i < WQ + 3 * XQ) {
      int j = i - WQ;
      if (j < XQ) cvt_quad(xq + j * 4, xqb + j * 4);
      else if (j < 2 * XQ) cvt_quad(xk + (j - XQ) * 4, xkb + (j - XQ) * 4);
      else cvt_quad(xv + (j - 2 * XQ) * 4, xvb + (j - 2 * XQ) * 4);
    } else if (i < WQ + 3 * XQ + RP) {
      int j = i - WQ - 3 * XQ;
      int t = j >> 5, f = j & 31;
      double inv = pow(10000.0, -(double)f / 32.0);
      double a = (double)t * inv;
      ropec[j] = (float)cos(a);
      ropes[j] = (float)sin(a);
    } else {
      vtp_pad[i - WQ - 3 * XQ - RP] = 0;   // zero 512B tail pad of vtp
    }
  }
}

// ---------------- RoPE table (fallback path) ----------------
__global__ void rope_tab(float* __restrict__ cosd, float* __restrict__ sind) {
  int i = blockIdx.x * blockDim.x + threadIdx.x;
  if (i >= T_DIM * 32) return;
  int t = i >> 5, f = i & 31;
  double inv = pow(10000.0, -(double)f / 32.0);
  double a = (double)t * inv;
  cosd[i] = (float)cos(a);
  sind[i] = (float)sin(a);
}

// ---------------- fused Q/K/V projection GEMM (bf16, BK=64, 2-barrier, swizzled) ----------------
// R11-proven structure (best measured). LDS [128 rows][8 chunks of 16B]:
// slot s of row r holds global chunk s^(r&7); XOR on frag read.
__global__ __launch_bounds__(256, 2) void proj_gemm(
    const short* __restrict__ xqb, const short* __restrict__ xkb,
    const short* __restrict__ xvb, const short* __restrict__ wbf_all,
    const float* __restrict__ qb, const float* __restrict__ kb,
    const float* __restrict__ vb,
    short* __restrict__ qpk, short* __restrict__ kpk, short* __restrict__ vtp,
    const float* __restrict__ ropec, const float* __restrict__ ropes, int mode_base) {
  int mode = mode_base + blockIdx.y;
  const short* xbf = mode == 0 ? xqb : (mode == 1 ? xkb : xvb);
  const short* W = wbf_all + mode * 1048576;
  const float* bias = mode == 0 ? qb : (mode == 1 ? kb : vb);

  int id = blockIdx.x;
  int w = (id & 7) * 63 + (id >> 3);   // XCD c owns contiguous work ids
  int n0 = (w & 7) * 128;
  int m0 = (w >> 3) * 128;
  __shared__ short As[128 * 64];   // 16 KB
  __shared__ short Bs[128 * 64];   // 16 KB
  int tid = threadIdx.x;
  int l = tid & 63, wid = tid >> 6;
  int wr = wid >> 1, wc = wid & 1;
  int lane16 = l & 15, lgrp = l >> 4;

  f4 acc[4][4];
#pragma unroll
  for (int i = 0; i < 4; ++i)
#pragma unroll
    for (int j = 0; j < 4; ++j)
#pragma unroll
      for (int r = 0; r < 4; ++r) acc[i][j][r] = 0.f;

  for (int kt = 0; kt < 16; ++kt) {
    int k0 = kt * 64;
#pragma unroll
    for (int j = 0; j < 4; ++j) {
      int idx = tid + j * 256;       // 0..1023
      int r = idx >> 3, s = idx & 7;
      int c = s ^ (r & 7);           // global chunk held in slot s
      int gm = m0 + r; gm = gm < M_DIM ? gm : (M_DIM - 1);
      gload_lds16(xbf + gm * 1024 + k0 + c * 8, As + idx * 8);
      gload_lds16(W + (n0 + r) * 1024 + k0 + c * 8, Bs + idx * 8);
    }
    __syncthreads();
    b8 af[2][4], bf[2][4];
#pragma unroll
    for (int kk = 0; kk < 2; ++kk) {
#pragma unroll
      for (int mf = 0; mf < 4; ++mf) {
        int row = wr * 64 + mf * 16 + lane16;
        af[kk][mf] = *(const b8*)(As + row * 64 + ((((kk << 2) + lgrp) ^ (row & 7)) << 3));
      }
#pragma unroll
      for (int nf = 0; nf < 4; ++nf) {
        int row = wc * 64 + nf * 16 + lane16;
        bf[kk][nf] = *(const b8*)(Bs + row * 64 + ((((kk << 2) + lgrp) ^ (row & 7)) << 3));
      }
    }
#pragma unroll
    for (int kk = 0; kk < 2; ++kk)
#pragma unroll
      for (int mf = 0; mf < 4; ++mf)
#pragma unroll
        for (int nf = 0; nf < 4; ++nf)
          acc[mf][nf] = __builtin_amdgcn_mfma_f32_16x16x32_bf16(af[kk][mf], bf[kk][nf], acc[mf][nf], 0, 0, 0);
    __syncthreads();
  }

  // epilogue
  int h = (n0 + wc * 64) >> 6;  // head index, uniform per wave
  float bv[4];
#pragma unroll
  for (int nf = 0; nf < 4; ++nf) bv[nf] = bias[n0 + wc * 64 + nf * 16 + lane16];
  const float qs = 0.125f * 1.44269504088896f;  // fold 1/ln2 into Q scale

#pragma unroll
  for (int mf = 0; mf < 4; ++mf) {
#pragma unroll
    for (int r = 0; r < 4; ++r) {
      int gm = m0 + wr * 64 + mf * 16 + lgrp * 4 + r;
      bool valid = gm < M_DIM;
      int t = gm >> 3, bb = gm & 7;
      int tc = t < T_DIM ? t : (T_DIM - 1);
      float x0 = acc[mf][0][r] + bv[0];
      float x1 = acc[mf][1][r] + bv[1];
      float x2 = acc[mf][2][r] + bv[2];
      float x3 = acc[mf][3][r] + bv[3];
      if (mode == 0) { x0 *= qs; x1 *= qs; x2 *= qs; x3 *= qs; }
      if (mode < 2) {
        float c0 = ropec[tc * 32 + lane16],      s0 = ropes[tc * 32 + lane16];
        float c1 = ropec[tc * 32 + 16 + lane16], s1 = ropes[tc * 32 + 16 + lane16];
        float y0 = c0 * x0 - s0 * x2;
        float y2 = c0 * x2 + s0 * x0;
        float y1 = c1 * x1 - s1 * x3;
        float y3 = c1 * x3 + s1 * x1;
        if (valid) {
          short* dst = (mode == 0 ? qpk : kpk) + (bb * 16 + h) * 64000 + t * 64;
          dst[lane16]      = f2bf(y0);
          dst[16 + lane16] = f2bf(y1);
          dst[32 + lane16] = f2bf(y2);
          dst[48 + lane16] = f2bf(y3);
        }
      } else if (valid) {
        short* dst = vtp + (bb * 16 + h) * 64000 + t;
        dst[(lane16) * 1000]      = f2bf(x0);
        dst[(16 + lane16) * 1000] = f2bf(x1);
        dst[(32 + lane16) * 1000] = f2bf(x2);
        dst[(48 + lane16) * 1000] = f2bf(x3);
      }
    }
  }
}

// ---------------- fused flash attention (32x32 MFMA, pipelined, max-free) ----------------
__global__ __launch_bounds__(256, 4) void attn_fused(
    const short* __restrict__ qpk, const short* __restrict__ kpk,
    const short* __restrict__ vtp, short* __restrict__ apk) {
  int id = blockIdx.x;
  int xcd = id & 7, seq = id >> 3;
  int bh = xcd * 16 + (seq >> 3);   // 16 heads per XCD, 8 q-tiles each
  int q0 = (seq & 7) * 128;
  int tid = threadIdx.x;
  int l = tid & 63, wid = tid >> 6;
  int l31 = l & 31, hi = l >> 5, l7 = l & 7;
  int qg = q0 + wid * 32 + l31;     // this lane's q (output column)

  __shared__ short Ks[2][64 * 64];  // [k-local][hd], 16B-chunk XOR-swizzled
  __shared__ short Vs[2][64 * 64];  // [d][k-local], 16B-chunk XOR-swizzled

  const short* qh = qpk + bh * 64000;
  const short* kh = kpk + bh * 64000;
  const short* vh = vtp + bh * 64000;

  int srow = tid >> 3;   // staging row (0..31; +32 on second pass)
  int sslot = tid & 7;   // 16B slot within 128B row

  // Q B-frags (hoisted): bq[hc] = Q[q=qg][hd = hc*16 + hi*8 .. +8]
  b8 bq[4];
  {
    int t = qg < T_DIM ? qg : (T_DIM - 1);
#pragma unroll
    for (int hc = 0; hc < 4; ++hc)
      bq[hc] = *(const b8*)(qh + t * 64 + hc * 16 + hi * 8);
  }

  float lrun = 0.f;
  f16v o0, o1;   // O^T[d][q=l31]
#pragma unroll
  for (int i = 0; i < 16; ++i) { o0[i] = 0.f; o1[i] = 0.f; }

  auto stageK = [&](int st, int buf) {
    int s0 = st * 64;
#pragma unroll
    for (int j = 0; j < 2; ++j) {
      int r = srow + j * 32;
      int c = sslot ^ (r & 7);
      gload_lds16(kh + (s0 + r) * 64 + c * 8, &Ks[buf][(j * 256 + tid) * 8]);
    }
  };
  auto stageV = [&](int st, int buf) {
    int s0 = st * 64;
#pragma unroll
    for (int j = 0; j < 2; ++j) {
      int r = srow + j * 32;
      int c = sslot ^ (r & 7);
      gload_lds16(vh + r * 1000 + s0 + c * 8, &Vs[buf][(j * 256 + tid) * 8]);
    }
  };

  // prologue: K(0), V(0), K(1) staged; QK(0) computed into regs
  stageK(0, 0);
  stageV(0, 0);
  stageK(1, 1);
  __syncthreads();

  f16v c0v, c1v;   // S^T for current tile: k 0..31 / 32..63, col q=l31
#pragma unroll
  for (int i = 0; i < 16; ++i) { c0v[i] = 0.f; c1v[i] = 0.f; }
#pragma unroll
  for (int hc = 0; hc < 4; ++hc) {
    int slot = ((2 * hc + hi) ^ l7) << 3;
    b8 a0 = *(const b8*)(Ks[0] + l31 * 64 + slot);
    b8 a1 = *(const b8*)(Ks[0] + (32 + l31) * 64 + slot);
    c0v = __builtin_amdgcn_mfma_f32_32x32x16_bf16(a0, bq[hc], c0v, 0, 0, 0);
    c1v = __builtin_amdgcn_mfma_f32_32x32x16_bf16(a1, bq[hc], c1v, 0, 0, 0);
  }
  // RACE FIX: all waves must finish reading Ks[0] (prologue QK) before any
  // wave's iter-0 stageK(2,0) write can land in Ks[0].
  __syncthreads();

  for (int i = 0; i < 16; ++i) {
    int b = i & 1;
    // stage next tiles early (free buffers this iter: Ks[b], Vs[b^1])
    if (i < 14) stageK(i + 2, b);
    if (i < 15) stageV(i + 1, b ^ 1);

    if (i == 15) {   // mask global k >= 1000 (k-local >= 40): c1v regs 4..15
#pragma unroll
      for (int r = 4; r < 16; ++r) c1v[r] = -1e30f;
    }

    // max-free softmax: P = exp2(S) in place
#pragma unroll
    for (int j = 0; j < 16; ++j) {
      c0v[j] = __builtin_amdgcn_exp2f(c0v[j]);
      c1v[j] = __builtin_amdgcn_exp2f(c1v[j]);
    }
    // partial row-sum (this lane's 32 k's); cross-hi combine deferred
    float ts[8];
#pragma unroll
    for (int j = 0; j < 8; ++j) ts[j] = (c0v[j] + c0v[j + 8]) + (c1v[j] + c1v[j + 8]);
#pragma unroll
    for (int d = 4; d > 0; d >>= 1)
#pragma unroll
      for (int j = 0; j < d; ++j) ts[j] += ts[j + d];
    lrun += ts[0];

    // pack P -> bf16 B-frags via cvt_pk + permlane32_swap
    unsigned u0[8], u1[8];
#pragma unroll
    for (int j = 0; j < 8; ++j) {
      u0[j] = cvt_pk_bf16(c0v[2 * j], c0v[2 * j + 1]);
      u1[j] = cvt_pk_bf16(c1v[2 * j], c1v[2 * j + 1]);
    }
    union { unsigned u[4]; b8 v; } pf[4];
    {
      auto w0 = __builtin_amdgcn_permlane32_swap(u0[0], u0[2], false, false);
      auto w1 = __builtin_amdgcn_permlane32_swap(u0[1], u0[3], false, false);
      pf[0].u[0] = w0[0]; pf[0].u[1] = w1[0]; pf[0].u[2] = w0[1]; pf[0].u[3] = w1[1];
      auto w2 = __builtin_amdgcn_permlane32_swap(u0[4], u0[6], false, false);
      auto w3 = __builtin_amdgcn_permlane32_swap(u0[5], u0[7], false, false);
      pf[1].u[0] = w2[0]; pf[1].u[1] = w3[0]; pf[1].u[2] = w2[1]; pf[1].u[3] = w3[1];
      auto w4 = __builtin_amdgcn_permlane32_swap(u1[0], u1[2], false, false);
      auto w5 = __builtin_amdgcn_permlane32_swap(u1[1], u1[3], false, false);
      pf[2].u[0] = w4[0]; pf[2].u[1] = w5[0]; pf[2].u[2] = w4[1]; pf[2].u[3] = w5[1];
      auto w6 = __builtin_amdgcn_permlane32_swap(u1[4], u1[6], false, false);
      auto w7 = __builtin_amdgcn_permlane32_swap(u1[5], u1[7], false, false);
      pf[3].u[0] = w6[0]; pf[3].u[1] = w7[0]; pf[3].u[2] = w6[1]; pf[3].u[3] = w7[1];
    }

    // QK(i+1) into freed c regs (consumed next iter -> full pipeline distance)
    if (i < 15) {
      const short* Kb = Ks[b ^ 1];
#pragma unroll
      for (int j = 0; j < 16; ++j) { c0v[j] = 0.f; c1v[j] = 0.f; }
      __builtin_amdgcn_s_setprio(1);
#pragma unroll
      for (int hc = 0; hc < 4; ++hc) {
        int slot = ((2 * hc + hi) ^ l7) << 3;
        b8 a0 = *(const b8*)(Kb + l31 * 64 + slot);
        b8 a1 = *(const b8*)(Kb + (32 + l31) * 64 + slot);
        c0v = __builtin_amdgcn_mfma_f32_32x32x16_bf16(a0, bq[hc], c0v, 0, 0, 0);
        c1v = __builtin_amdgcn_mfma_f32_32x32x16_bf16(a1, bq[hc], c1v, 0, 0, 0);
      }
      __builtin_amdgcn_s_setprio(0);
    }

    // PV(i): O^T += V^T P^T
    {
      const short* Vb = Vs[b];
      __builtin_amdgcn_s_setprio(1);
#pragma unroll
      for (int ck = 0; ck < 4; ++ck) {
        int slot = ((2 * ck + hi) ^ l7) << 3;
        b8 av0 = *(const b8*)(Vb + l31 * 64 + slot);
        b8 av1 = *(const b8*)(Vb + (32 + l31) * 64 + slot);
        o0 = __builtin_amdgcn_mfma_f32_32x32x16_bf16(av0, pf[ck].v, o0, 0, 0, 0);
        o1 = __builtin_amdgcn_mfma_f32_32x32x16_bf16(av1, pf[ck].v, o1, 0, 0, 0);
      }
      __builtin_amdgcn_s_setprio(0);
    }
    __syncthreads();
  }

  // epilogue: combine lrun across hi halves; lane owns q = qg
  lrun += __shfl_xor(lrun, 32, 64);
  if (qg < T_DIM) {
    float linv = 1.f / lrun;
    int bb = bh >> 4, hh = bh & 15;
    short* dst = apk + (qg * 8 + bb) * 1024 + hh * 64;
#pragma unroll
    for (int rq = 0; rq < 4; ++rq) {
      int d0 = 8 * rq + 4 * hi;
      short4 w0, w1;
      w0.x = f2bf(o0[rq * 4 + 0] * linv);
      w0.y = f2bf(o0[rq * 4 + 1] * linv);
      w0.z = f2bf(o0[rq * 4 + 2] * linv);
      w0.w = f2bf(o0[rq * 4 + 3] * linv);
      w1.x = f2bf(o1[rq * 4 + 0] * linv);
      w1.y = f2bf(o1[rq * 4 + 1] * linv);
      w1.z = f2bf(o1[rq * 4 + 2] * linv);
      w1.w = f2bf(o1[rq * 4 + 3] * linv);
      *(short4*)(dst + d0) = w0;
      *(short4*)(dst + 32 + d0) = w1;
    }
  }
}

// ---------------- output projection GEMM (BK=64, 2-barrier, swizzled) ----------------
__global__ __launch_bounds__(256, 2) void out_gemm(
    const short* __restrict__ apk, const short* __restrict__ wo,
    const float* __restrict__ ob, float* __restrict__ out) {
  int id = blockIdx.x;
  int w = (id & 7) * 63 + (id >> 3);   // XCD-contiguous work index
  int n0 = (w & 7) * 128;
  int m0 = (w >> 3) * 128;
  __shared__ short As[128 * 64];
  __shared__ short Bs[128 * 64];
  int tid = threadIdx.x;
  int l = tid & 63, wid = tid >> 6;
  int wr = wid >> 1, wc = wid & 1;
  int lane16 = l & 15, lgrp = l >> 4;

  f4 acc[4][4];
#pragma unroll
  for (int i = 0; i < 4; ++i)
#pragma unroll
    for (int j = 0; j < 4; ++j)
#pragma unroll
      for (int r = 0; r < 4; ++r) acc[i][j][r] = 0.f;

  for (int kt = 0; kt < 16; ++kt) {
    int k0 = kt * 64;
#pragma unroll
    for (int j = 0; j < 4; ++j) {
      int idx = tid + j * 256;
      int r = idx >> 3, s = idx & 7;
      int c = s ^ (r & 7);
      int gm = m0 + r; gm = gm < M_DIM ? gm : (M_DIM - 1);
      gload_lds16(apk + gm * 1024 + k0 + c * 8, As + idx * 8);
      gload_lds16(wo + (n0 + r) * 1024 + k0 + c * 8, Bs + idx * 8);
    }
    __syncthreads();
    b8 af[2][4], bf[2][4];
#pragma unroll
    for (int kk = 0; kk < 2; ++kk) {
#pragma unroll
      for (int mf = 0; mf < 4; ++mf) {
        int row = wr * 64 + mf * 16 + lane16;
        af[kk][mf] = *(const b8*)(As + row * 64 + ((((kk << 2) + lgrp) ^ (row & 7)) << 3));
      }
#pragma unroll
      for (int nf = 0; nf < 4; ++nf) {
        int row = wc * 64 + nf * 16 + lane16;
        bf[kk][nf] = *(const b8*)(Bs + row * 64 + ((((kk << 2) + lgrp) ^ (row & 7)) << 3));
      }
    }
#pragma unroll
    for (int kk = 0; kk < 2; ++kk)
#pragma unroll
      for (int mf = 0; mf < 4; ++mf)
#pragma unroll
        for (int nf = 0; nf < 4; ++nf)
          acc[mf][nf] = __builtin_amdgcn_mfma_f32_16x16x32_bf16(af[kk][mf], bf[kk][nf], acc[mf][nf], 0, 0, 0);
    __syncthreads();
  }

  float bv[4];
#pragma unroll
  for (int nf = 0; nf < 4; ++nf) bv[nf] = ob[n0 + wc * 64 + nf * 16 + lane16];
#pragma unroll
  for (int mf = 0; mf < 4; ++mf) {
#pragma unroll
    for (int r = 0; r < 4; ++r) {
      int gm = m0 + wr * 64 + mf * 16 + lgrp * 4 + r;
      if (gm < M_DIM) {
#pragma unroll
        for (int nf = 0; nf < 4; ++nf)
          out[gm * 1024 + n0 + wc * 64 + nf * 16 + lane16] = acc[mf][nf][r] + bv[nf];
      }
    }
  }
}

// ---------------- launch ----------------
extern "C" void kernel_launch(void* const* d_in, const int* in_sizes, int n_in,
                              void* d_out, int out_size, void* d_ws, size_t ws_size,
                              hipStream_t stream) {
  const float* xq = (const float*)d_in[0];
  const float* xk = (const float*)d_in[1];
  const float* xv = (const float*)d_in[2];
  const float* qw = (const float*)d_in[3];
  const float* kw = (const float*)d_in[4];
  const float* vw = (const float*)d_in[5];
  const float* ow = (const float*)d_in[6];
  const float* qb = (const float*)d_in[7];
  const float* kb = (const float*)d_in[8];
  const float* vb = (const float*)d_in[9];
  const float* ob = (const float*)d_in[10];
  float* out = (float*)d_out;
  char* ws = (char*)d_ws;

  // base workspace layout (~74.2 MB)
  short* wbf   = (short*)(ws);                         // 4 * 1Mi bf16 = 8 MB
  float* ropec = (float*)(ws + 8388608);               // 32000 f32
  float* ropes = (float*)(ws + 8516608);               // 32000 f32
  short* qpk   = (short*)(ws + 8644608);               // (BH,T,HD) bf16
  short* kpk   = (short*)(ws + 8644608 + 16384512);
  short* vtp   = (short*)(ws + 8644608 + 2 * 16384512);// (BH,HD,T) bf16 (+512B pad)
  short* apk   = (short*)(ws + 8644608 + 3 * 16384512);// (T*B,E) bf16
  const size_t BASE = 8644608 + (size_t)4 * 16384512;  // 74,182,656

  const size_t XB = (size_t)M_DIM * E_DIM * 2;         // 16,384,000 B per bf16 X
  if (ws_size >= BASE + 3 * XB) {
    // fused path: prep (converts + rope + pad) -> 3-mode proj -> attn -> out
    short* xqb = (short*)(ws + BASE);
    short* xkb = (short*)(ws + BASE + XB);
    short* xvb = (short*)(ws + BASE + 2 * XB);
    prep_all<<<2048, 256, 0, stream>>>(qw, kw, vw, ow, xq, xk, xv, wbf, xqb, xkb, xvb,
                                       vtp + 8192000, ropec, ropes);
    proj_gemm<<<dim3(504, 3), dim3(256), 0, stream>>>(xqb, xkb, xvb, wbf, qb, kb, vb,
                                                      qpk, kpk, vtp, ropec, ropes, 0);
  } else {
    // fallback: proven alternating sequence, xbf shares the apk slot
    hipMemsetAsync((char*)vtp + 2 * 8192000, 0, 512, stream);
    rope_tab<<<125, 256, 0, stream>>>(ropec, ropes);
    short* xbf = apk;
    convert_w<<<2048, 256, 0, stream>>>(qw, kw, vw, ow, wbf);
    const float* xs[3] = {xq, xk, xv};
    for (int mode = 0; mode < 3; ++mode) {
      convert_x<<<2048, 256, 0, stream>>>(xs[mode], xbf);
      proj_gemm<<<dim3(504, 1), dim3(256), 0, stream>>>(xbf, xbf, xbf, wbf, qb, kb, vb,
                                                        qpk, kpk, vtp, ropec, ropes, mode);
    }
  }
  attn_fused<<<dim3(1024), dim3(256), 0, stream>>>(qpk, kpk, vtp, apk);
  out_gemm<<<dim3(504), dim3(256), 0, stream>>>(apk, wbf + 3 * 1048576, ob, out);
}